// Round 5
// baseline (574.718 us; speedup 1.0000x reference)
//
#include <hip/hip_runtime.h>
#include <hip/hip_bf16.h>

#define DIMD 2048
#define NHD 16
#define QLORA 1536
#define KVLORA 512
#define QKD 192
#define BBD 2
#define SSD 2048
#define BSD (BBD*SSD)       // 4096 tokens
#define KVPAD 640           // 576 padded to multiple of 128
#define BHN (BBD*NHD)       // 32 (b,h) pairs
#define EPSF 1.1920929e-07f
#define SCALEF 0.07216878364870322f  // 192^-0.5

typedef __hip_bfloat16 bf16;
typedef __attribute__((ext_vector_type(8))) short short8;
typedef __attribute__((ext_vector_type(4))) float floatx4;

typedef __attribute__((address_space(1))) char as1_char;
typedef __attribute__((address_space(3))) char as3_char;
#define GLD16(g, l) __builtin_amdgcn_global_load_lds((as1_char*)(g), (as3_char*)(l), 16, 0, 0)

// ---------------- block reduction (256 threads = 4 waves) ----------------
__device__ __forceinline__ float block_sum(float x) {
#pragma unroll
  for (int o = 32; o > 0; o >>= 1) x += __shfl_xor(x, o, 64);
  __shared__ float red[4];
  __syncthreads();
  if ((threadIdx.x & 63) == 0) red[threadIdx.x >> 6] = x;
  __syncthreads();
  return red[0] + red[1] + red[2] + red[3];
}

// ---------------- generic bf16 MFMA GEMM:  C = A(MxK) * B(NxK)^T + bias ----------------
template<bool STORE_BF16>
__global__ __launch_bounds__(256)
void gemm_bt(const bf16* __restrict__ A, const bf16* __restrict__ Bm,
             const float* __restrict__ bias, void* __restrict__ Cp,
             int M, int N, int K, long sA, long sB, long sC, int ldc)
{
  int m0 = blockIdx.y * 128, n0 = blockIdx.x * 128;
  long z = blockIdx.z;
  A  += z * sA;
  Bm += z * sB;

  __shared__ __align__(16) bf16 Asm[128 * 32];
  __shared__ __align__(16) bf16 Bsm[128 * 32];

  const int tid  = threadIdx.x;
  const int lane = tid & 63;
  const int wv   = tid >> 6;
  const int wm   = (wv >> 1) << 6;
  const int wn   = (wv & 1) << 6;
  const int fr   = lane & 15;
  const int q8   = (lane >> 4) << 3;

  floatx4 acc[4][4];
#pragma unroll
  for (int i = 0; i < 4; ++i)
#pragma unroll
    for (int j = 0; j < 4; ++j)
      acc[i][j] = (floatx4){0.f, 0.f, 0.f, 0.f};

  for (int k0 = 0; k0 < K; k0 += 32) {
    __syncthreads();
#pragma unroll
    for (int it = 0; it < 2; ++it) {
      int seg = it * 256 + tid;
      int row = seg >> 2, cs = seg & 3;
      GLD16(A  + (long)(m0 + row) * K + k0 + cs * 8, &Asm[(it * 256 + wv * 64) * 8]);
      GLD16(Bm + (long)(n0 + row) * K + k0 + cs * 8, &Bsm[(it * 256 + wv * 64) * 8]);
    }
    __syncthreads();

    short8 fa[4], fb[4];
#pragma unroll
    for (int t = 0; t < 4; ++t) fa[t] = *(const short8*)&Asm[(wm + t * 16 + fr) * 32 + q8];
#pragma unroll
    for (int t = 0; t < 4; ++t) fb[t] = *(const short8*)&Bsm[(wn + t * 16 + fr) * 32 + q8];
#pragma unroll
    for (int i = 0; i < 4; ++i)
#pragma unroll
      for (int j = 0; j < 4; ++j)
        acc[i][j] = __builtin_amdgcn_mfma_f32_16x16x32_bf16(fa[i], fb[j], acc[i][j], 0, 0, 0);
  }

  long cb = z * sC;
  int rq = (lane >> 4) * 4;
#pragma unroll
  for (int i = 0; i < 4; ++i) {
#pragma unroll
    for (int j = 0; j < 4; ++j) {
      int col = n0 + wn + j * 16 + fr;
      float bv = bias ? bias[col] : 0.f;
#pragma unroll
      for (int r = 0; r < 4; ++r) {
        int rowg = m0 + wm + i * 16 + rq + r;
        float v = acc[i][j][r] + bv;
        if (STORE_BF16)
          ((bf16*)Cp)[cb + (long)rowg * ldc + col] = __float2bfloat16(v);
        else
          ((float*)Cp)[cb + (long)rowg * ldc + col] = v;
      }
    }
  }
}

// ---------------- fused flash attention (causal), balanced tile pairs ----------------
// 512 blocks x 256 threads. Q-tile = 64 rows (4 waves x 16 rows), K-tile = 128 cols.
// Tiles qt in 0..31 have qt/2+1 causal j-iters; block p does pair {31-p, p}:
// exactly 17 iters per block. LDS 80KB -> exactly 2 blocks/CU on ALL 256 CUs.
__global__ __launch_bounds__(256, 2)
void flash_attn(const bf16* __restrict__ Qh, const bf16* __restrict__ Kh,
                const bf16* __restrict__ Vt, bf16* __restrict__ attnall)
{
  const int p = blockIdx.x;        // 0..15
  const int z = blockIdx.y;        // b*NH + h
  const int b = z >> 4, h = z & 15;

  const bf16* Qg = Qh + (long)z * SSD * QKD;
  const bf16* Kg = Kh + (long)z * SSD * QKD;
  const bf16* Vg = Vt + (long)z * 128 * SSD;

  __shared__ __align__(16) bf16 Ksm[6 * 4096];  // 48KB: 6 chunks x 128 rows x 32; P+Q alias
  __shared__ __align__(16) bf16 Vsm[4 * 4096];  // 32KB: 4 chunks x 128 rows x 32
  bf16* Psm = Ksm;                              // P: 4 chunks x 64 rows x 32 (stride 4096)

  const int tid  = threadIdx.x;
  const int lane = tid & 63;
  const int wv   = tid >> 6;       // 0..3
  const int fr   = lane & 15;
  const int g4   = lane >> 4;
  const int q8   = g4 << 3;

#pragma unroll 1
  for (int t = 0; t < 2; ++t) {
    const int qt = t ? p : 31 - p;   // heavy tile first
    const int q0 = qt * 64;
    const int jmax = qt >> 1;        // last 128-col K-tile touching the causal region

    __syncthreads();  // prior tile's LDS reads complete
    // --- stage Q (64 x 192) through Ksm, pull fragments to regs ---
#pragma unroll
    for (int c = 0; c < 6; ++c) {
      int row = tid >> 2, cs = tid & 3;
      GLD16(Qg + (long)(q0 + row) * QKD + c * 32 + cs * 8, &Ksm[c * 4096 + wv * 512]);
    }
    __syncthreads();
    short8 qf[6];
#pragma unroll
    for (int c = 0; c < 6; ++c)
      qf[c] = *(const short8*)&Ksm[c * 4096 + (wv * 16 + fr) * 32 + q8];

    floatx4 oacc[8];
#pragma unroll
    for (int n = 0; n < 8; ++n) oacc[n] = (floatx4){0.f, 0.f, 0.f, 0.f};
    float mi[4], li[4];
#pragma unroll
    for (int r = 0; r < 4; ++r) { mi[r] = -1e30f; li[r] = 0.f; }

    for (int j = 0; j <= jmax; ++j) {
      const int jb = j * 128;
      __syncthreads();  // qf reads / prev-iter P & V reads complete
#pragma unroll
      for (int c = 0; c < 6; ++c)
#pragma unroll
        for (int it = 0; it < 2; ++it) {
          int seg = it * 256 + tid;
          int row = seg >> 2, cs = seg & 3;
          GLD16(Kg + (long)(jb + row) * QKD + c * 32 + cs * 8,
                &Ksm[c * 4096 + it * 2048 + wv * 512]);
        }
#pragma unroll
      for (int c = 0; c < 4; ++c)
#pragma unroll
        for (int it = 0; it < 2; ++it) {
          int seg = it * 256 + tid;
          int row = seg >> 2, cs = seg & 3;
          GLD16(Vg + (long)row * SSD + jb + c * 32 + cs * 8,
                &Vsm[c * 4096 + it * 2048 + wv * 512]);
        }
      __syncthreads();  // drains vmcnt

      // ---- S = Q K^T : this wave's 16 rows x 128 cols ----
      floatx4 sacc[8];
#pragma unroll
      for (int n = 0; n < 8; ++n) sacc[n] = (floatx4){0.f, 0.f, 0.f, 0.f};
#pragma unroll
      for (int c = 0; c < 6; ++c) {
#pragma unroll
        for (int n = 0; n < 8; ++n) {
          short8 fb = *(const short8*)&Ksm[c * 4096 + (n * 16 + fr) * 32 + q8];
          sacc[n] = __builtin_amdgcn_mfma_f32_16x16x32_bf16(qf[c], fb, sacc[n], 0, 0, 0);
        }
      }

      // ---- online softmax (rows fully inside this wave; 16-lane reductions) ----
      const bool diag = (j == jmax);
#pragma unroll
      for (int r = 0; r < 4; ++r) {
        int rowg = q0 + wv * 16 + g4 * 4 + r;
        float mx = -1e30f;
#pragma unroll
        for (int n = 0; n < 8; ++n) {
          float v = sacc[n][r] * SCALEF;
          if (diag && (jb + n * 16 + fr) > rowg) v = -1e30f;
          sacc[n][r] = v;
          mx = fmaxf(mx, v);
        }
#pragma unroll
        for (int off = 1; off < 16; off <<= 1) mx = fmaxf(mx, __shfl_xor(mx, off, 64));
        float mnew = fmaxf(mi[r], mx);
        float alpha = __expf(mi[r] - mnew);
        mi[r] = mnew;
        float rs = 0.f;
#pragma unroll
        for (int n = 0; n < 8; ++n) {
          float pv = __expf(sacc[n][r] - mnew);
          sacc[n][r] = pv;
          rs += pv;
        }
#pragma unroll
        for (int off = 1; off < 16; off <<= 1) rs += __shfl_xor(rs, off, 64);
        li[r] = li[r] * alpha + rs;
#pragma unroll
        for (int n = 0; n < 8; ++n) oacc[n][r] *= alpha;
      }

      // ---- P -> LDS (C/D layout -> A-operand layout), aliasing dead K region ----
      __syncthreads();  // all waves done reading Ksm fragments
#pragma unroll
      for (int n = 0; n < 8; ++n) {
        int c2 = n >> 1;
        int col = (n & 1) * 16 + fr;
#pragma unroll
        for (int r = 0; r < 4; ++r) {
          int m = wv * 16 + g4 * 4 + r;
          Psm[c2 * 4096 + m * 32 + col] = __float2bfloat16(sacc[n][r]);
        }
      }
      // same-wave write->read ordering via compiler-inserted lgkmcnt

      // ---- O += P V ----
#pragma unroll
      for (int c2 = 0; c2 < 4; ++c2) {
        short8 pf = *(const short8*)&Psm[c2 * 4096 + (wv * 16 + fr) * 32 + q8];
#pragma unroll
        for (int dn = 0; dn < 8; ++dn) {
          short8 vf = *(const short8*)&Vsm[c2 * 4096 + (dn * 16 + fr) * 32 + q8];
          oacc[dn] = __builtin_amdgcn_mfma_f32_16x16x32_bf16(pf, vf, oacc[dn], 0, 0, 0);
        }
      }
    }

    // ---- normalize and write O directly in (B,S,NH*128) layout ----
#pragma unroll
    for (int r = 0; r < 4; ++r) {
      float inv = 1.f / li[r];
      int m = q0 + wv * 16 + g4 * 4 + r;
      bf16* orow = attnall + ((long)(b * SSD + m) * NHD + h) * 128;
#pragma unroll
      for (int dn = 0; dn < 8; ++dn)
        orow[dn * 16 + fr] = __float2bfloat16(oacc[dn][r] * inv);
    }
  }
}

// ---------------- fused fp32 -> bf16 converts (float4-vectorized) ----------------
__device__ __forceinline__ void cvt4(const float* __restrict__ s, bf16* __restrict__ d,
                                     long se, long de) {
  float4 v = *(const float4*)(s + se);
  union { bf16 h[4]; uint2 u; } o;
  o.h[0] = __float2bfloat16(v.x); o.h[1] = __float2bfloat16(v.y);
  o.h[2] = __float2bfloat16(v.z); o.h[3] = __float2bfloat16(v.w);
  *(uint2*)(d + de) = o.u;
}

#define NX4   ((long)BSD * DIMD / 4)
#define NQD4  ((long)QLORA * DIMD / 4)
#define NQU4  ((long)3072 * QLORA / 4)
#define NKVD4 ((long)KVPAD * DIMD / 4)
#define NKVU4 ((long)4096 * KVLORA / 4)
#define NWO4  ((long)DIMD * 2048 / 4)

__global__ __launch_bounds__(256)
void cvt_all(const float* __restrict__ x, const float* __restrict__ wqd,
             const float* __restrict__ wqu, const float* __restrict__ wkvd,
             const float* __restrict__ wkvu, const float* __restrict__ wo,
             bf16* __restrict__ dx, bf16* __restrict__ dwqd, bf16* __restrict__ dwqu,
             bf16* __restrict__ dwkvd, bf16* __restrict__ dwkvu, bf16* __restrict__ dwo)
{
  long i = (long)blockIdx.x * 256 + threadIdx.x;
  if (i < NX4) { cvt4(x, dx, i * 4, i * 4); return; }
  i -= NX4;
  if (i < NQD4) { cvt4(wqd, dwqd, i * 4, i * 4); return; }
  i -= NQD4;
  if (i < NQU4) { cvt4(wqu, dwqu, i * 4, i * 4); return; }
  i -= NQU4;
  if (i < NKVD4) {
    long e = i * 4;
    long r = e >> 11;             // dst row (cols = 2048)
    if (r < 576) cvt4(wkvd, dwkvd, e, e);
    else *(uint2*)(dwkvd + e) = (uint2){0u, 0u};
    return;
  }
  i -= NKVD4;
  if (i < NKVU4) { cvt4(wkvu, dwkvu, i * 4, i * 4); return; }
  i -= NKVU4;
  if (i < NWO4) { cvt4(wo, dwo, i * 4, i * 4); return; }
}

// ---------------- cos/sin table: freqs (S x 32) -> float2 table ----------------
__global__ void trig_k(const float* __restrict__ freqs, float2* __restrict__ tab)
{
  int i = blockIdx.x * 256 + threadIdx.x;
  if (i < SSD * 32) {
    float f = freqs[i];
    tab[i] = make_float2(cosf(f), sinf(f));
  }
}

// ---------------- rmsnorm (row per block), bf16 in (+opt fp32 bias), bf16 out ----------------
template<int L>
__global__ __launch_bounds__(256)
void rmsnorm_k(const bf16* __restrict__ in, const float* __restrict__ bias,
               const float* __restrict__ w, bf16* __restrict__ out, int ldin)
{
  constexpr int NIT = L / 256;
  long r = blockIdx.x;
  const bf16* row = in + r * ldin;
  int tid = threadIdx.x;
  float v[NIT];
  float ss = 0.f;
#pragma unroll
  for (int i = 0; i < NIT; ++i) {
    int c = tid + (i << 8);
    float x = __bfloat162float(row[c]) + (bias ? bias[c] : 0.f);
    v[i] = x;
    ss += x * x;
  }
  ss = block_sum(ss);
  float sc = rsqrtf(ss / (float)L + EPSF);
#pragma unroll
  for (int i = 0; i < NIT; ++i) {
    int c = tid + (i << 8);
    out[r * L + c] = __float2bfloat16(v[i] * sc * w[c]);
  }
}

// ---------------- build Q (rope on last 64) -> (B,NH,S,192) bf16 ----------------
__global__ void build_q(const bf16* __restrict__ Qf, const float2* __restrict__ cstab,
                        bf16* __restrict__ Qh)
{
  int idx = blockIdx.x * 256 + threadIdx.x;
  if (idx >= BSD * NHD * 96) return;
  int j = idx % 96;
  int h = (idx / 96) % NHD;
  int srow = idx / (96 * NHD);
  int s = srow & (SSD - 1);
  int b = srow >> 11;
  const bf16* src = Qf + (long)srow * (NHD * QKD) + h * QKD + 2 * j;
  float x0 = __bfloat162float(src[0]), x1 = __bfloat162float(src[1]), y0, y1;
  if (j >= 64) {
    int i = j - 64;
    float2 cs = cstab[s * 32 + i];
    y0 = x0 * cs.x - x1 * cs.y;
    y1 = x0 * cs.y + x1 * cs.x;
  } else { y0 = x0; y1 = x1; }
  bf16* dst = Qh + ((long)(b * NHD + h) * SSD + s) * QKD + 2 * j;
  dst[0] = __float2bfloat16(y0);
  dst[1] = __float2bfloat16(y1);
}

// ---------------- build K = [K_nope | rope(K_rope) bcast] -> (B,NH,S,192) bf16 ----------------
__global__ void build_k(const bf16* __restrict__ kvf, const bf16* __restrict__ kvkr,
                        const float* __restrict__ kvb, const float2* __restrict__ cstab,
                        bf16* __restrict__ Kh)
{
  int idx = blockIdx.x * 256 + threadIdx.x;
  if (idx >= BSD * NHD * 96) return;
  int j = idx % 96;
  int h = (idx / 96) % NHD;
  int srow = idx / (96 * NHD);
  int s = srow & (SSD - 1);
  int b = srow >> 11;
  float y0, y1;
  if (j < 64) {
    const bf16* src = kvf + (long)srow * 4096 + h * 256 + 2 * j;
    y0 = __bfloat162float(src[0]); y1 = __bfloat162float(src[1]);
  } else {
    int i = j - 64;
    float x0 = __bfloat162float(kvkr[(long)srow * KVPAD + 512 + 2 * i]) + kvb[512 + 2 * i];
    float x1 = __bfloat162float(kvkr[(long)srow * KVPAD + 513 + 2 * i]) + kvb[513 + 2 * i];
    float2 cs = cstab[s * 32 + i];
    y0 = x0 * cs.x - x1 * cs.y;
    y1 = x0 * cs.y + x1 * cs.x;
  }
  bf16* dst = Kh + ((long)(b * NHD + h) * SSD + s) * QKD + 2 * j;
  dst[0] = __float2bfloat16(y0);
  dst[1] = __float2bfloat16(y1);
}

// ---------------- build V^T: kv(B,S,NH,256)[...,128:256] -> Vt (BH,128,S) bf16 ----------------
__global__ __launch_bounds__(256)
void build_vt(const bf16* __restrict__ kvf, bf16* __restrict__ Vt)
{
  __shared__ float t[32][33];
  int s0 = blockIdx.x * 32, d0 = blockIdx.y * 32, z = blockIdx.z;
  int b = z / NHD, h = z % NHD;
  int tx = threadIdx.x, ty = threadIdx.y;  // 32 x 8
#pragma unroll
  for (int r = 0; r < 4; ++r) {
    int sl = ty + r * 8;
    t[sl][tx] = __bfloat162float(kvf[(long)(b * SSD + s0 + sl) * 4096 + h * 256 + 128 + d0 + tx]);
  }
  __syncthreads();
#pragma unroll
  for (int r = 0; r < 4; ++r) {
    int dl = ty + r * 8;
    Vt[((long)z * 128 + d0 + dl) * SSD + s0 + tx] = __float2bfloat16(t[tx][dl]);
  }
}

// ---------------- diagnostic: ws too small ----------------
__global__ void diag_fill(float* out) { out[blockIdx.x * 256 + threadIdx.x] = 1000.0f; }

extern "C" void kernel_launch(void* const* d_in, const int* in_sizes, int n_in,
                              void* d_out, int out_size, void* d_ws, size_t ws_size,
                              hipStream_t stream)
{
  const float* x     = (const float*)d_in[0];
  const float* freqs = (const float*)d_in[1];
  const float* Wqd   = (const float*)d_in[3];
  const float* Wqdb  = (const float*)d_in[4];
  const float* qnw   = (const float*)d_in[5];
  const float* Wqu   = (const float*)d_in[6];
  const float* Wqub  = (const float*)d_in[7];
  const float* Wkvd  = (const float*)d_in[8];
  const float* Wkvdb = (const float*)d_in[9];
  const float* kvnw  = (const float*)d_in[10];
  const float* Wkvu  = (const float*)d_in[11];
  const float* Wkvub = (const float*)d_in[12];
  const float* Wo    = (const float*)d_in[13];
  const float* Wob   = (const float*)d_in[14];
  float* out = (float*)d_out;

  char* ws = (char*)d_ws;
  size_t off = 0;
  auto alloc = [&](size_t bytes) {
    void* p = ws + off;
    off += (bytes + 255) & ~(size_t)255;
    return p;
  };

  bf16* Wqd16  = (bf16*)alloc((size_t)QLORA * DIMD * 2);
  bf16* Wqu16  = (bf16*)alloc((size_t)3072 * QLORA * 2);
  bf16* Wkvd16 = (bf16*)alloc((size_t)KVPAD * DIMD * 2);
  bf16* Wkvu16 = (bf16*)alloc((size_t)4096 * KVLORA * 2);
  bf16* Wo16   = (bf16*)alloc((size_t)DIMD * 2048 * 2);
  bf16* x16    = (bf16*)alloc((size_t)BSD * DIMD * 2);
  bf16* Ra     = (bf16*)alloc((size_t)BSD * QLORA * 2);   // qdown, then kvkr
  bf16* Rb     = (bf16*)alloc((size_t)BSD * QLORA * 2);   // qlat, then kvlat
  bf16* Rc     = (bf16*)alloc((size_t)BSD * 4096 * 2);    // Qf, then kvf, then attnall
  bf16* Qh16   = (bf16*)alloc((size_t)BHN * SSD * QKD * 2);
  bf16* Kh16   = (bf16*)alloc((size_t)BHN * SSD * QKD * 2);
  bf16* Vt16   = (bf16*)alloc((size_t)BHN * 128 * SSD * 2);
  float2* cstab = (float2*)alloc((size_t)SSD * 32 * sizeof(float2));

  bf16* qdown   = Ra;  bf16* kvkr    = Ra;
  bf16* qlat16  = Rb;  bf16* kvlat16 = Rb;
  bf16* Qf      = Rc;  bf16* kvf     = Rc;  bf16* attnall = Rc;

  if (off > ws_size) { diag_fill<<<8, 256, 0, stream>>>(out); return; }

  dim3 blk(256);
  auto cdiv = [](long a, long b) { return (int)((a + b - 1) / b); };

  // --- all fp32->bf16 converts in one dispatch; trig table ---
  long tot4 = NX4 + NQD4 + NQU4 + NKVD4 + NKVU4 + NWO4;
  cvt_all<<<cdiv(tot4, 256), blk, 0, stream>>>(x, Wqd, Wqu, Wkvd, Wkvu, Wo,
                                               x16, Wqd16, Wqu16, Wkvd16, Wkvu16, Wo16);
  trig_k<<<cdiv((long)SSD * 32, 256), blk, 0, stream>>>(freqs, cstab);

  // --- Q path ---
  gemm_bt<true><<<dim3(QLORA / 128, BSD / 128, 1), blk, 0, stream>>>(
      x16, Wqd16, Wqdb, qdown, BSD, QLORA, DIMD, 0, 0, 0, QLORA);
  rmsnorm_k<QLORA><<<BSD, blk, 0, stream>>>(qdown, nullptr, qnw, qlat16, QLORA);
  gemm_bt<true><<<dim3(3072 / 128, BSD / 128, 1), blk, 0, stream>>>(
      qlat16, Wqu16, Wqub, Qf, BSD, 3072, QLORA, 0, 0, 0, 3072);
  build_q<<<cdiv((long)BSD * NHD * 96, 256), blk, 0, stream>>>(Qf, cstab, Qh16);

  // --- KV path ---
  gemm_bt<true><<<dim3(KVPAD / 128, BSD / 128, 1), blk, 0, stream>>>(
      x16, Wkvd16, nullptr, kvkr, BSD, KVPAD, DIMD, 0, 0, 0, KVPAD);
  rmsnorm_k<KVLORA><<<BSD, blk, 0, stream>>>(kvkr, Wkvdb, kvnw, kvlat16, KVPAD);
  gemm_bt<true><<<dim3(4096 / 128, BSD / 128, 1), blk, 0, stream>>>(
      kvlat16, Wkvu16, Wkvub, kvf, BSD, 4096, KVLORA, 0, 0, 0, 4096);
  build_k<<<cdiv((long)BSD * NHD * 96, 256), blk, 0, stream>>>(kvf, kvkr, Wkvdb, cstab, Kh16);
  build_vt<<<dim3(SSD / 32, 128 / 32, BHN), dim3(32, 8), 0, stream>>>(kvf, Vt16);

  // --- balanced fused flash attention: writes O directly in (B,S,NH*128) ---
  flash_attn<<<dim3(16, BHN), blk, 0, stream>>>(Qh16, Kh16, Vt16, attnall);

  // --- output projection (fp32 out) ---
  gemm_bt<false><<<dim3(2048 / 128, BSD / 128, 1), blk, 0, stream>>>(
      attnall, Wo16, Wob, out, BSD, DIMD, 2048, 0, 0, 0, DIMD);
}